// Round 4
// baseline (270.685 us; speedup 1.0000x reference)
//
#include <hip/hip_runtime.h>
#include <math.h>

typedef unsigned short u16;
typedef __attribute__((ext_vector_type(8))) short short8;   // 8 bf16 = 4 VGPRs
typedef __attribute__((ext_vector_type(4))) short short4v;  // 4 bf16 = 2 VGPRs
typedef __attribute__((ext_vector_type(4))) float f32x4;    // MFMA C/D frag
typedef __attribute__((ext_vector_type(2))) unsigned int uint2v;

constexpr int Bn = 4, Sn = 2048, Dn = 1024, Hn = 16;
constexpr float SCL = 0.125f * 1.44269504f;  // 1/sqrt(64) * log2(e), folded into Wq

__device__ __forceinline__ u16 f2bf(float f) {  // RNE float->bf16
  unsigned u = __float_as_uint(f);
  u += 0x7fffu + ((u >> 16) & 1u);
  return (u16)(u >> 16);
}

__device__ __forceinline__ f32x4 mfma32(short8 a, short8 b, f32x4 c) {
  return __builtin_amdgcn_mfma_f32_16x16x32_bf16(a, b, c, 0, 0, 0);
}

// 16x16x16 bf16 MFMA with builtin-name fallback chain (instruction exists on
// gfx950 per ISA §10); last resort emulates via zero-padded 16x16x32 (exact).
__device__ __forceinline__ f32x4 mfma16(short4v a, short4v b, f32x4 c) {
#if __has_builtin(__builtin_amdgcn_mfma_f32_16x16x16_bf16)
  return __builtin_amdgcn_mfma_f32_16x16x16_bf16(a, b, c, 0, 0, 0);
#elif __has_builtin(__builtin_amdgcn_mfma_f32_16x16x16bf16_1k)
  return __builtin_amdgcn_mfma_f32_16x16x16bf16_1k(a, b, c, 0, 0, 0);
#else
  short8 a8 = {a[0], a[1], a[2], a[3], 0, 0, 0, 0};
  short8 b8 = {b[0], b[1], b[2], b[3], 0, 0, 0, 0};
  return __builtin_amdgcn_mfma_f32_16x16x32_bf16(a8, b8, c, 0, 0, 0);
#endif
}

__device__ __forceinline__ void gl_lds16(const u16* g, u16* l) {
  __builtin_amdgcn_global_load_lds(
      (const __attribute__((address_space(1))) unsigned int*)g,
      (__attribute__((address_space(3))) unsigned int*)l, 16, 0, 0);
}

// ---------------------------------------------------------------------------
// One launch for all f32->bf16 casts. Blocks 0..8191: x. Then 1024 each for
// wq (pre-scaled by SCL), wk, wv, wo.
// ---------------------------------------------------------------------------
__global__ __launch_bounds__(256) void cast_all(
    const float4* __restrict__ x, const float4* __restrict__ wq,
    const float4* __restrict__ wk, const float4* __restrict__ wv,
    const float4* __restrict__ wo, ushort4* __restrict__ xb,
    ushort4* __restrict__ wqb, ushort4* __restrict__ wkb,
    ushort4* __restrict__ wvb, ushort4* __restrict__ wob) {
  const int blk = blockIdx.x;
  const float4* in;
  ushort4* out;
  int base;
  float s = 1.0f;
  if (blk < 8192) {
    in = x; out = xb; base = blk;
  } else if (blk < 9216) {
    in = wq; out = wqb; base = blk - 8192; s = SCL;
  } else if (blk < 10240) {
    in = wk; out = wkb; base = blk - 9216;
  } else if (blk < 11264) {
    in = wv; out = wvb; base = blk - 10240;
  } else {
    in = wo; out = wob; base = blk - 11264;
  }
  const int i = base * 256 + threadIdx.x;
  const float4 f = in[i];
  ushort4 o;
  o.x = f2bf(f.x * s); o.y = f2bf(f.y * s);
  o.z = f2bf(f.z * s); o.w = f2bf(f.w * s);
  out[i] = o;
}

// ---------------------------------------------------------------------------
// C[m,n] = sum_k A[m,k]*W[n,k], bf16 in. 128x128 tile, BK=64, 4 waves.
// m97 two-barrier structure (R1's, which measured <=73 us for all 3 QKV
// GEMMs; the R3 "2-phase" experiment at 2 blocks/CU was slower -- LDS
// doubled by per-instantiation __shared__, occupancy crash). Fixes here:
//  - LDS declared ONCE at kernel scope, passed as pointers -> gemm_qkv's
//    two gemm_body instantiations share one 32 KB allocation (was 64 KB).
//  - BK=64: halves barrier count per K-loop vs R1's BK=32; 32 KB total
//    keeps the VGPR-bound ~3 blocks/CU occupancy. Swizzle cl^(row&7)
//    (correctness verified in R2's run).
// MODE 0: bf16 natural; MODE 1: f32 natural; MODE 2: bf16 into vt2 = V^T
// tiles [hd][key] (64x64 per (b,h,jt)), 16B chunks XOR-swizzled by hd
// (matches attn's identity-copy LDS staging + swizzled reads).
// ---------------------------------------------------------------------------
template <int MODE>
__device__ __forceinline__ void gemm_body(const u16* __restrict__ A,
                                          const u16* __restrict__ W,
                                          u16* __restrict__ Cb,
                                          float* __restrict__ Cf,
                                          int bx, int by,
                                          u16* __restrict__ Asm,
                                          u16* __restrict__ Wsm) {
  const int t = threadIdx.x;
  const int w = t >> 6, l = t & 63;
  const int wy = w >> 1, wx = w & 1;
  const int q = l >> 4, r = l & 15;
  const int m0 = bx * 128, n0 = by * 128;

  f32x4 acc[4][4] = {};

  for (int k0 = 0; k0 < 1024; k0 += 64) {
    __syncthreads();
#pragma unroll
    for (int i = 0; i < 4; ++i) {
      const int c = t + i * 256;            // 16B chunk id, 0..1023
      const int row = c >> 3, cl = c & 7;   // 8 chunks per 128B row
      const int cg = cl ^ (row & 7);        // pre-swizzled global source
      gl_lds16(A + (size_t)(m0 + row) * 1024 + k0 + cg * 8, &Asm[c * 8]);
      gl_lds16(W + (size_t)(n0 + row) * 1024 + k0 + cg * 8, &Wsm[c * 8]);
    }
    __syncthreads();
#pragma unroll
    for (int kf = 0; kf < 2; ++kf) {
      short8 af[4], bf[4];
#pragma unroll
      for (int mi = 0; mi < 4; ++mi) {
        const int rowA = wy * 64 + mi * 16 + r;
        af[mi] = *(const short8*)&Asm[rowA * 64 + ((kf * 4 + q) ^ (rowA & 7)) * 8];
        const int rowB = wx * 64 + mi * 16 + r;
        bf[mi] = *(const short8*)&Wsm[rowB * 64 + ((kf * 4 + q) ^ (rowB & 7)) * 8];
      }
#pragma unroll
      for (int mi = 0; mi < 4; ++mi)
#pragma unroll
        for (int ni = 0; ni < 4; ++ni)
          acc[mi][ni] = mfma32(af[mi], bf[ni], acc[mi][ni]);
    }
  }

  if (MODE == 2) {
    // acc[mi][ni][e]: token = m0+wy*64+mi*16+q*4+e, feat = n0+wx*64+ni*16+r.
    // -> vt2 tile (b, h, jt): V^T[hd=ni*16+r][key=mi*16+q*4+e], stored as
    // 16B chunks c2 = q + 4*(mi>>1) at slot c2^(hd&7), half (mi&1).
    const int bq = m0 >> 11;
    const int jt = ((m0 & 2047) >> 6) + wy;
    const int hh = (n0 >> 6) + wx;
    u16* vt_t = Cb + ((size_t)((bq * 16 + hh) * 32) + jt) * 4096;
#pragma unroll
    for (int mi = 0; mi < 4; ++mi)
#pragma unroll
      for (int ni = 0; ni < 4; ++ni) {
        short4v pk;
#pragma unroll
        for (int e = 0; e < 4; ++e) pk[e] = (short)f2bf(acc[mi][ni][e]);
        const int hd = ni * 16 + r;
        const int c2 = q + 4 * (mi >> 1);
        *(short4v*)&vt_t[hd * 64 + ((c2 ^ (r & 7)) * 8) + (mi & 1) * 4] = pk;
      }
    return;
  }

#pragma unroll
  for (int mi = 0; mi < 4; ++mi) {
    const int row = m0 + wy * 64 + mi * 16 + q * 4;
#pragma unroll
    for (int ni = 0; ni < 4; ++ni) {
      const int col = n0 + wx * 64 + ni * 16 + r;
#pragma unroll
      for (int e = 0; e < 4; ++e) {
        if (MODE == 1)
          Cf[(size_t)(row + e) * 1024 + col] = acc[mi][ni][e];
        else
          Cb[(size_t)(row + e) * 1024 + col] = f2bf(acc[mi][ni][e]);
      }
    }
  }
}

__global__ __launch_bounds__(256) void gemm_qkv(const u16* __restrict__ A,
                                                const u16* __restrict__ Wq,
                                                const u16* __restrict__ Wk,
                                                const u16* __restrict__ Wv,
                                                u16* __restrict__ Cq,
                                                u16* __restrict__ Ck,
                                                u16* __restrict__ Vt) {
  __shared__ u16 Asm[128 * 64];
  __shared__ u16 Wsm[128 * 64];
  const int z = blockIdx.z;
  if (z == 2)
    gemm_body<2>(A, Wv, Vt, nullptr, blockIdx.x, blockIdx.y, Asm, Wsm);
  else
    gemm_body<0>(A, z ? Wk : Wq, z ? Ck : Cq, nullptr, blockIdx.x, blockIdx.y,
                 Asm, Wsm);
}

__global__ __launch_bounds__(256) void gemm_out(const u16* __restrict__ A,
                                                const u16* __restrict__ W,
                                                float* __restrict__ C) {
  __shared__ u16 Asm[128 * 64];
  __shared__ u16 Wsm[128 * 64];
  gemm_body<1>(A, W, nullptr, C, blockIdx.x, blockIdx.y, Asm, Wsm);
}

// ---------------------------------------------------------------------------
// Flash attention v8 = v6 body, UNPAIRED grid. v6 counters (occupancy 17% =
// 2 waves/SIMD) show the GRID was the occupancy limiter: 1024 blocks x 2
// waves = exactly 4 blocks/CU, while LDS (32 KB -> 5 blocks/CU) and VGPR
// (104) allow more. Now 2048 blocks, ONE 64-row q-tile each (st = 31-k:
// heavy tiles first in dispatch order, so backfill absorbs the causal
// imbalance), XCD pinning kept (all blocks of group g land on XCD g%8).
// Same per-tile code: double-buffered K/V^T LDS staging via gl_lds16,
// register softmax via S^T trick, scale pre-folded into Wq, cvt_pk packing,
// setprio on MFMA. (v7's LDS-free variant spilled to scratch: LDS staging
// is the register-pressure valve, keep it.)
// ---------------------------------------------------------------------------
__global__ __launch_bounds__(128) void attn_v8(const u16* __restrict__ Qb,
                                               const u16* __restrict__ Kb,
                                               const u16* __restrict__ Vt,
                                               u16* __restrict__ Ob) {
  const int i = blockIdx.x;            // 0..2047
  const int xcd = i & 7;
  const int k = (i >> 3) & 31;         // tile slot, dispatch-ordered
  const int gl = i >> 8;               // 0..7: group-within-XCD
  const int grp = xcd + 8 * gl;        // (b,h) group 0..63, pinned to XCD
  const int st = 31 - k;               // heavy tiles dispatched first
  const int b = grp >> 4, h = grp & 15;
  const int t = threadIdx.x;
  const int w = t >> 6, l = t & 63;
  const int q = l >> 4, r = l & 15;

  __shared__ u16 Kd[2][4096];
  __shared__ u16 Vd[2][4096];

  const size_t kgbase = (size_t)(b * Sn) * Dn + h * 64;
  const size_t vgbase = (size_t)((b * Hn + h) * 32) * 4096;

  // Per-thread global staging pointers.
  const u16* kg[4];
  const u16* vg[4];
#pragma unroll
  for (int ii = 0; ii < 4; ++ii) {
    const int c = t + ii * 128, row = c >> 3, cl = c & 7;
    kg[ii] = Kb + kgbase + (size_t)row * Dn + (cl ^ (row & 7)) * 8;
    vg[ii] = Vt + vgbase + c * 8;
  }
  // Hoisted LDS read bases (elements). K kf=0/1 and V np=0/1 use the same
  // swizzle: base = r*64 + ((kf*4+q)^(r&7))*8.
  const int rx = r & 7;
  const int b0 = r * 64 + ((q ^ rx) * 8);
  const int b1 = r * 64 + (((4 + q) ^ rx) * 8);

  const int qb64 = st * 64;

  // Q B-frags (n = qrow = lane&15, k = hd = quad*8+j); Q pre-scaled by SCL
  short8 Qf[2][2];
#pragma unroll
  for (int mi = 0; mi < 2; ++mi)
#pragma unroll
    for (int kf = 0; kf < 2; ++kf)
      Qf[mi][kf] = *(const short8*)(Qb +
          (size_t)(b * Sn + qb64 + w * 32 + mi * 16 + r) * Dn + h * 64 +
          kf * 32 + q * 8);

  f32x4 O[2][4] = {};
  float l_[2] = {0.f, 0.f};

  // prologue: stage tile 0 -> buf 0
#pragma unroll
  for (int ii = 0; ii < 4; ++ii) {
    const int c8 = (t + ii * 128) * 8;
    gl_lds16(kg[ii], &Kd[0][c8]);
    gl_lds16(vg[ii], &Vd[0][c8]);
  }
  // Running prefetch pointers for tiles 1..st.
  const u16* kgt[4];
  const u16* vgt[4];
#pragma unroll
  for (int ii = 0; ii < 4; ++ii) {
    kgt[ii] = kg[ii] + 64 * Dn;
    vgt[ii] = vg[ii] + 4096;
  }

  for (int jt = 0; jt <= st; ++jt) {
    __syncthreads();  // vmcnt(0) drain: tile jt staged (overlapped prev iter)
    if (jt < st) {    // prefetch tile jt+1 into the other buffer
      u16* kl = &Kd[(jt + 1) & 1][0];
      u16* vl = &Vd[(jt + 1) & 1][0];
#pragma unroll
      for (int ii = 0; ii < 4; ++ii) {
        const int c8 = (t + ii * 128) * 8;
        gl_lds16(kgt[ii], kl + c8);
        gl_lds16(vgt[ii], vl + c8);
        kgt[ii] += 64 * Dn;
        vgt[ii] += 4096;
      }
    }
    const u16* KtA = &Kd[jt & 1][b0];
    const u16* KtB = &Kd[jt & 1][b1];

    // K A-frags (m = key = lane&15, k = hd): 2 bases + imm offsets
    short8 Kf[4][2];
#pragma unroll
    for (int ni = 0; ni < 4; ++ni) {
      Kf[ni][0] = *(const short8*)(KtA + ni * 1024);
      Kf[ni][1] = *(const short8*)(KtB + ni * 1024);
    }

    // S^T[key][qrow]: A=K, B=Q (already includes softmax scale via Wq)
    f32x4 S[2][4] = {};
    __builtin_amdgcn_s_setprio(1);
#pragma unroll
    for (int ni = 0; ni < 4; ++ni)
#pragma unroll
      for (int kf = 0; kf < 2; ++kf) {
        S[0][ni] = mfma32(Kf[ni][kf], Qf[0][kf], S[0][ni]);
        S[1][ni] = mfma32(Kf[ni][kf], Qf[1][kf], S[1][ni]);
      }
    __builtin_amdgcn_s_setprio(0);

    // causal mask on diagonal tile (local: key = ni*16+q*4+e, row = w*32+mi*16+r)
    if (jt == st) {
#pragma unroll
      for (int mi = 0; mi < 2; ++mi) {
        const int qrow = w * 32 + mi * 16 + r;
#pragma unroll
        for (int ni = 0; ni < 4; ++ni) {
          const int key = ni * 16 + q * 4;
#pragma unroll
          for (int e = 0; e < 4; ++e)
            if (key + e > qrow) S[mi][ni][e] = -3.0e38f;
        }
      }
    }

    // exp2 (scale pre-folded) -> P^T B-frags packed via v_cvt_pk_bf16_f32
    short4v Pf[2][4];
#pragma unroll
    for (int mi = 0; mi < 2; ++mi)
#pragma unroll
      for (int ni = 0; ni < 4; ++ni) {
        const float p0 = __builtin_amdgcn_exp2f(S[mi][ni][0]);
        const float p1 = __builtin_amdgcn_exp2f(S[mi][ni][1]);
        const float p2 = __builtin_amdgcn_exp2f(S[mi][ni][2]);
        const float p3 = __builtin_amdgcn_exp2f(S[mi][ni][3]);
        l_[mi] += (p0 + p1) + (p2 + p3);
        unsigned plo, phi;
        asm("v_cvt_pk_bf16_f32 %0, %1, %2" : "=v"(plo) : "v"(p0), "v"(p1));
        asm("v_cvt_pk_bf16_f32 %0, %1, %2" : "=v"(phi) : "v"(p2), "v"(p3));
        const uint2v pk2 = {plo, phi};
        Pf[mi][ni] = __builtin_bit_cast(short4v, pk2);
      }

    // O^T += V^T * P^T  (V A-frags from swizzled LDS tile: 2 bases + imms)
    const u16* VsA = &Vd[jt & 1][b0];
    const u16* VsB = &Vd[jt & 1][b1];
    __builtin_amdgcn_s_setprio(1);
#pragma unroll
    for (int np = 0; np < 2; ++np)
#pragma unroll
      for (int ni2 = 0; ni2 < 4; ++ni2) {
        const short8 vv =
            *(const short8*)((np ? VsB : VsA) + ni2 * 1024);
        const short4v va = {vv[0], vv[1], vv[2], vv[3]};    // keys ni=2np
        const short4v vb2 = {vv[4], vv[5], vv[6], vv[7]};   // keys ni=2np+1
        O[0][ni2] = mfma16(va, Pf[0][2 * np], O[0][ni2]);
        O[0][ni2] = mfma16(vb2, Pf[0][2 * np + 1], O[0][ni2]);
        O[1][ni2] = mfma16(va, Pf[1][2 * np], O[1][ni2]);
        O[1][ni2] = mfma16(vb2, Pf[1][2 * np + 1], O[1][ni2]);
      }
    __builtin_amdgcn_s_setprio(0);
  }

  // epilogue: reduce l over quads, scale, packed 8B stores
#pragma unroll
  for (int mi = 0; mi < 2; ++mi) {
    float s = l_[mi];
    s += __shfl_xor(s, 16, 64);
    s += __shfl_xor(s, 32, 64);
    const float rl = __builtin_amdgcn_rcpf(s);
#pragma unroll
    for (int ni2 = 0; ni2 < 4; ++ni2) {
      short4v o;
#pragma unroll
      for (int e = 0; e < 4; ++e) o[e] = (short)f2bf(O[mi][ni2][e] * rl);
      *(short4v*)(Ob + (size_t)(b * Sn + qb64 + w * 32 + mi * 16 + r) * Dn +
                  h * 64 + ni2 * 16 + q * 4) = o;
    }
  }
}

// ---------------------------------------------------------------------------
extern "C" void kernel_launch(void* const* d_in, const int* in_sizes, int n_in,
                              void* d_out, int out_size, void* d_ws, size_t ws_size,
                              hipStream_t stream) {
  const float* x  = (const float*)d_in[0];
  const float* wq = (const float*)d_in[1];
  const float* wk = (const float*)d_in[2];
  const float* wv = (const float*)d_in[3];
  const float* wo = (const float*)d_in[4];
  float* out = (float*)d_out;

  u16* xb  = (u16*)d_ws;            // 8M u16
  u16* wqb = xb + 8388608;
  u16* wkb = wqb + 1048576;
  u16* wvb = wkb + 1048576;
  u16* wob = wvb + 1048576;
  u16* qb  = wob + 1048576;         // 8M each
  u16* kb  = qb + 8388608;
  u16* vt2 = kb + 8388608;          // V^T tiles, pre-swizzled
  u16* aob = vt2 + 8388608;

  cast_all<<<12288, 256, 0, stream>>>(
      (const float4*)x, (const float4*)wq, (const float4*)wk,
      (const float4*)wv, (const float4*)wo, (ushort4*)xb, (ushort4*)wqb,
      (ushort4*)wkb, (ushort4*)wvb, (ushort4*)wob);

  gemm_qkv<<<dim3(64, 8, 3), 256, 0, stream>>>(xb, wqb, wkb, wvb, qb, kb, vt2);

  attn_v8<<<2048, 128, 0, stream>>>(qb, kb, vt2, aob);

  gemm_out<<<dim3(64, 8), 256, 0, stream>>>(aob, wob, out);
}

// Round 5
// 240.822 us; speedup vs baseline: 1.1240x; 1.1240x over previous
//
#include <hip/hip_runtime.h>
#include <math.h>

typedef unsigned short u16;
typedef __attribute__((ext_vector_type(8))) short short8;   // 8 bf16 = 4 VGPRs
typedef __attribute__((ext_vector_type(4))) short short4v;  // 4 bf16 = 2 VGPRs
typedef __attribute__((ext_vector_type(4))) float f32x4;    // MFMA C/D frag
typedef __attribute__((ext_vector_type(2))) unsigned int uint2v;

constexpr int Bn = 4, Sn = 2048, Dn = 1024, Hn = 16;
constexpr float SCL = 0.125f * 1.44269504f;  // 1/sqrt(64) * log2(e), folded into Wq

__device__ __forceinline__ u16 f2bf(float f) {  // RNE float->bf16
  unsigned u = __float_as_uint(f);
  u += 0x7fffu + ((u >> 16) & 1u);
  return (u16)(u >> 16);
}

__device__ __forceinline__ f32x4 mfma32(short8 a, short8 b, f32x4 c) {
  return __builtin_amdgcn_mfma_f32_16x16x32_bf16(a, b, c, 0, 0, 0);
}

// 16x16x16 bf16 MFMA with builtin-name fallback chain (instruction exists on
// gfx950 per ISA §10); last resort emulates via zero-padded 16x16x32 (exact).
__device__ __forceinline__ f32x4 mfma16(short4v a, short4v b, f32x4 c) {
#if __has_builtin(__builtin_amdgcn_mfma_f32_16x16x16_bf16)
  return __builtin_amdgcn_mfma_f32_16x16x16_bf16(a, b, c, 0, 0, 0);
#elif __has_builtin(__builtin_amdgcn_mfma_f32_16x16x16bf16_1k)
  return __builtin_amdgcn_mfma_f32_16x16x16bf16_1k(a, b, c, 0, 0, 0);
#else
  short8 a8 = {a[0], a[1], a[2], a[3], 0, 0, 0, 0};
  short8 b8 = {b[0], b[1], b[2], b[3], 0, 0, 0, 0};
  return __builtin_amdgcn_mfma_f32_16x16x32_bf16(a8, b8, c, 0, 0, 0);
#endif
}

__device__ __forceinline__ void gl_lds16(const u16* g, u16* l) {
  __builtin_amdgcn_global_load_lds(
      (const __attribute__((address_space(1))) unsigned int*)g,
      (__attribute__((address_space(3))) unsigned int*)l, 16, 0, 0);
}

// ---------------------------------------------------------------------------
// One launch for all f32->bf16 casts. Blocks 0..8191: x. Then 1024 each for
// wq (pre-scaled by SCL), wk, wv, wo.
// ---------------------------------------------------------------------------
__global__ __launch_bounds__(256) void cast_all(
    const float4* __restrict__ x, const float4* __restrict__ wq,
    const float4* __restrict__ wk, const float4* __restrict__ wv,
    const float4* __restrict__ wo, ushort4* __restrict__ xb,
    ushort4* __restrict__ wqb, ushort4* __restrict__ wkb,
    ushort4* __restrict__ wvb, ushort4* __restrict__ wob) {
  const int blk = blockIdx.x;
  const float4* in;
  ushort4* out;
  int base;
  float s = 1.0f;
  if (blk < 8192) {
    in = x; out = xb; base = blk;
  } else if (blk < 9216) {
    in = wq; out = wqb; base = blk - 8192; s = SCL;
  } else if (blk < 10240) {
    in = wk; out = wkb; base = blk - 9216;
  } else if (blk < 11264) {
    in = wv; out = wvb; base = blk - 10240;
  } else {
    in = wo; out = wob; base = blk - 11264;
  }
  const int i = base * 256 + threadIdx.x;
  const float4 f = in[i];
  ushort4 o;
  o.x = f2bf(f.x * s); o.y = f2bf(f.y * s);
  o.z = f2bf(f.z * s); o.w = f2bf(f.w * s);
  out[i] = o;
}

// ---------------------------------------------------------------------------
// C[m,n] = sum_k A[m,k]*W[n,k], bf16 in. 128x128 tile, BK=64, 4 waves.
// m97 two-barrier structure; LDS declared once at kernel scope (shared by
// both gemm_body instantiations in gemm_qkv). R4 verified this performs
// at R1 level (non-attn total identical). Swizzle cl^(row&7).
// MODE 0: bf16 natural; MODE 1: f32 natural; MODE 2: bf16 into vt2 = V^T
// tiles [hd][key] (64x64 per (b,h,jt)), 16B chunks XOR-swizzled by hd
// (matches attn's identity-copy LDS staging + swizzled reads).
// ---------------------------------------------------------------------------
template <int MODE>
__device__ __forceinline__ void gemm_body(const u16* __restrict__ A,
                                          const u16* __restrict__ W,
                                          u16* __restrict__ Cb,
                                          float* __restrict__ Cf,
                                          int bx, int by,
                                          u16* __restrict__ Asm,
                                          u16* __restrict__ Wsm) {
  const int t = threadIdx.x;
  const int w = t >> 6, l = t & 63;
  const int wy = w >> 1, wx = w & 1;
  const int q = l >> 4, r = l & 15;
  const int m0 = bx * 128, n0 = by * 128;

  f32x4 acc[4][4] = {};

  for (int k0 = 0; k0 < 1024; k0 += 64) {
    __syncthreads();
#pragma unroll
    for (int i = 0; i < 4; ++i) {
      const int c = t + i * 256;            // 16B chunk id, 0..1023
      const int row = c >> 3, cl = c & 7;   // 8 chunks per 128B row
      const int cg = cl ^ (row & 7);        // pre-swizzled global source
      gl_lds16(A + (size_t)(m0 + row) * 1024 + k0 + cg * 8, &Asm[c * 8]);
      gl_lds16(W + (size_t)(n0 + row) * 1024 + k0 + cg * 8, &Wsm[c * 8]);
    }
    __syncthreads();
#pragma unroll
    for (int kf = 0; kf < 2; ++kf) {
      short8 af[4], bf[4];
#pragma unroll
      for (int mi = 0; mi < 4; ++mi) {
        const int rowA = wy * 64 + mi * 16 + r;
        af[mi] = *(const short8*)&Asm[rowA * 64 + ((kf * 4 + q) ^ (rowA & 7)) * 8];
        const int rowB = wx * 64 + mi * 16 + r;
        bf[mi] = *(const short8*)&Wsm[rowB * 64 + ((kf * 4 + q) ^ (rowB & 7)) * 8];
      }
#pragma unroll
      for (int mi = 0; mi < 4; ++mi)
#pragma unroll
        for (int ni = 0; ni < 4; ++ni)
          acc[mi][ni] = mfma32(af[mi], bf[ni], acc[mi][ni]);
    }
  }

  if (MODE == 2) {
    // acc[mi][ni][e]: token = m0+wy*64+mi*16+q*4+e, feat = n0+wx*64+ni*16+r.
    // -> vt2 tile (b, h, jt): V^T[hd=ni*16+r][key=mi*16+q*4+e], stored as
    // 16B chunks c2 = q + 4*(mi>>1) at slot c2^(hd&7), half (mi&1).
    const int bq = m0 >> 11;
    const int jt = ((m0 & 2047) >> 6) + wy;
    const int hh = (n0 >> 6) + wx;
    u16* vt_t = Cb + ((size_t)((bq * 16 + hh) * 32) + jt) * 4096;
#pragma unroll
    for (int mi = 0; mi < 4; ++mi)
#pragma unroll
      for (int ni = 0; ni < 4; ++ni) {
        short4v pk;
#pragma unroll
        for (int e = 0; e < 4; ++e) pk[e] = (short)f2bf(acc[mi][ni][e]);
        const int hd = ni * 16 + r;
        const int c2 = q + 4 * (mi >> 1);
        *(short4v*)&vt_t[hd * 64 + ((c2 ^ (r & 7)) * 8) + (mi & 1) * 4] = pk;
      }
    return;
  }

#pragma unroll
  for (int mi = 0; mi < 4; ++mi) {
    const int row = m0 + wy * 64 + mi * 16 + q * 4;
#pragma unroll
    for (int ni = 0; ni < 4; ++ni) {
      const int col = n0 + wx * 64 + ni * 16 + r;
#pragma unroll
      for (int e = 0; e < 4; ++e) {
        if (MODE == 1)
          Cf[(size_t)(row + e) * 1024 + col] = acc[mi][ni][e];
        else
          Cb[(size_t)(row + e) * 1024 + col] = f2bf(acc[mi][ni][e]);
      }
    }
  }
}

__global__ __launch_bounds__(256) void gemm_qkv(const u16* __restrict__ A,
                                                const u16* __restrict__ Wq,
                                                const u16* __restrict__ Wk,
                                                const u16* __restrict__ Wv,
                                                u16* __restrict__ Cq,
                                                u16* __restrict__ Ck,
                                                u16* __restrict__ Vt) {
  __shared__ u16 Asm[128 * 64];
  __shared__ u16 Wsm[128 * 64];
  const int z = blockIdx.z;
  if (z == 2)
    gemm_body<2>(A, Wv, Vt, nullptr, blockIdx.x, blockIdx.y, Asm, Wsm);
  else
    gemm_body<0>(A, z ? Wk : Wq, z ? Ck : Cq, nullptr, blockIdx.x, blockIdx.y,
                 Asm, Wsm);
}

__global__ __launch_bounds__(256) void gemm_out(const u16* __restrict__ A,
                                                const u16* __restrict__ W,
                                                float* __restrict__ C) {
  __shared__ u16 Asm[128 * 64];
  __shared__ u16 Wsm[128 * 64];
  gemm_body<1>(A, W, nullptr, C, blockIdx.x, blockIdx.y, Asm, Wsm);
}

// ---------------------------------------------------------------------------
// Flash attention v9 = v8 body with GLOBAL LPT dispatch order. v8's
// regression (102 us, occupancy 12.3%) was an ordering bug: st was derived
// from LOW bits of blockIdx, so heavy (st=31) tiles appeared in EVERY
// 256-block stretch -- including the very end of the grid, giving a long
// single-block tail and poor mid-run residency (blocks vary 32:1 in
// duration with no longest-first order). Fix: tile slot in the HIGH bits.
//   slot = i >> 6  (0..31, dispatch-ordered)  ->  st = 31 - slot
//   grp  = (i & 7) + 8 * ((i >> 3) & 7)       (64 groups per slot)
// First 64 blocks = the 64 heaviest tiles (one per (b,h) group) -> CUs fill
// with long work first; tiny tiles dispatch last and backfill the tail
// (classic LPT). XCD pinning preserved (i & 7 == grp & 7). Max residency
// is LDS-bound at 5 blocks/CU (32 KB) vs v6's grid-bound 4.
// Per-tile code unchanged: double-buffered K/V^T LDS staging via gl_lds16,
// register softmax via S^T trick, scale pre-folded into Wq, cvt_pk packing,
// setprio on MFMA. (v7 showed LDS staging is the register-pressure valve.)
// ---------------------------------------------------------------------------
__global__ __launch_bounds__(128) void attn_v9(const u16* __restrict__ Qb,
                                               const u16* __restrict__ Kb,
                                               const u16* __restrict__ Vt,
                                               u16* __restrict__ Ob) {
  const int i = blockIdx.x;                      // 0..2047
  const int st = 31 - (i >> 6);                  // heavy q-tiles first (LPT)
  const int grp = (i & 7) + 8 * ((i >> 3) & 7);  // (b,h) group, XCD-pinned
  const int b = grp >> 4, h = grp & 15;
  const int t = threadIdx.x;
  const int w = t >> 6, l = t & 63;
  const int q = l >> 4, r = l & 15;

  __shared__ u16 Kd[2][4096];
  __shared__ u16 Vd[2][4096];

  const size_t kgbase = (size_t)(b * Sn) * Dn + h * 64;
  const size_t vgbase = (size_t)((b * Hn + h) * 32) * 4096;

  // Per-thread global staging pointers.
  const u16* kg[4];
  const u16* vg[4];
#pragma unroll
  for (int ii = 0; ii < 4; ++ii) {
    const int c = t + ii * 128, row = c >> 3, cl = c & 7;
    kg[ii] = Kb + kgbase + (size_t)row * Dn + (cl ^ (row & 7)) * 8;
    vg[ii] = Vt + vgbase + c * 8;
  }
  // Hoisted LDS read bases (elements). K kf=0/1 and V np=0/1 use the same
  // swizzle: base = r*64 + ((kf*4+q)^(r&7))*8.
  const int rx = r & 7;
  const int b0 = r * 64 + ((q ^ rx) * 8);
  const int b1 = r * 64 + (((4 + q) ^ rx) * 8);

  const int qb64 = st * 64;

  // Q B-frags (n = qrow = lane&15, k = hd = quad*8+j); Q pre-scaled by SCL
  short8 Qf[2][2];
#pragma unroll
  for (int mi = 0; mi < 2; ++mi)
#pragma unroll
    for (int kf = 0; kf < 2; ++kf)
      Qf[mi][kf] = *(const short8*)(Qb +
          (size_t)(b * Sn + qb64 + w * 32 + mi * 16 + r) * Dn + h * 64 +
          kf * 32 + q * 8);

  f32x4 O[2][4] = {};
  float l_[2] = {0.f, 0.f};

  // prologue: stage tile 0 -> buf 0
#pragma unroll
  for (int ii = 0; ii < 4; ++ii) {
    const int c8 = (t + ii * 128) * 8;
    gl_lds16(kg[ii], &Kd[0][c8]);
    gl_lds16(vg[ii], &Vd[0][c8]);
  }
  // Running prefetch pointers for tiles 1..st.
  const u16* kgt[4];
  const u16* vgt[4];
#pragma unroll
  for (int ii = 0; ii < 4; ++ii) {
    kgt[ii] = kg[ii] + 64 * Dn;
    vgt[ii] = vg[ii] + 4096;
  }

  for (int jt = 0; jt <= st; ++jt) {
    __syncthreads();  // vmcnt(0) drain: tile jt staged (overlapped prev iter)
    if (jt < st) {    // prefetch tile jt+1 into the other buffer
      u16* kl = &Kd[(jt + 1) & 1][0];
      u16* vl = &Vd[(jt + 1) & 1][0];
#pragma unroll
      for (int ii = 0; ii < 4; ++ii) {
        const int c8 = (t + ii * 128) * 8;
        gl_lds16(kgt[ii], kl + c8);
        gl_lds16(vgt[ii], vl + c8);
        kgt[ii] += 64 * Dn;
        vgt[ii] += 4096;
      }
    }
    const u16* KtA = &Kd[jt & 1][b0];
    const u16* KtB = &Kd[jt & 1][b1];

    // K A-frags (m = key = lane&15, k = hd): 2 bases + imm offsets
    short8 Kf[4][2];
#pragma unroll
    for (int ni = 0; ni < 4; ++ni) {
      Kf[ni][0] = *(const short8*)(KtA + ni * 1024);
      Kf[ni][1] = *(const short8*)(KtB + ni * 1024);
    }

    // S^T[key][qrow]: A=K, B=Q (already includes softmax scale via Wq)
    f32x4 S[2][4] = {};
    __builtin_amdgcn_s_setprio(1);
#pragma unroll
    for (int ni = 0; ni < 4; ++ni)
#pragma unroll
      for (int kf = 0; kf < 2; ++kf) {
        S[0][ni] = mfma32(Kf[ni][kf], Qf[0][kf], S[0][ni]);
        S[1][ni] = mfma32(Kf[ni][kf], Qf[1][kf], S[1][ni]);
      }
    __builtin_amdgcn_s_setprio(0);

    // causal mask on diagonal tile (local: key = ni*16+q*4+e, row = w*32+mi*16+r)
    if (jt == st) {
#pragma unroll
      for (int mi = 0; mi < 2; ++mi) {
        const int qrow = w * 32 + mi * 16 + r;
#pragma unroll
        for (int ni = 0; ni < 4; ++ni) {
          const int key = ni * 16 + q * 4;
#pragma unroll
          for (int e = 0; e < 4; ++e)
            if (key + e > qrow) S[mi][ni][e] = -3.0e38f;
        }
      }
    }

    // exp2 (scale pre-folded) -> P^T B-frags packed via v_cvt_pk_bf16_f32
    short4v Pf[2][4];
#pragma unroll
    for (int mi = 0; mi < 2; ++mi)
#pragma unroll
      for (int ni = 0; ni < 4; ++ni) {
        const float p0 = __builtin_amdgcn_exp2f(S[mi][ni][0]);
        const float p1 = __builtin_amdgcn_exp2f(S[mi][ni][1]);
        const float p2 = __builtin_amdgcn_exp2f(S[mi][ni][2]);
        const float p3 = __builtin_amdgcn_exp2f(S[mi][ni][3]);
        l_[mi] += (p0 + p1) + (p2 + p3);
        unsigned plo, phi;
        asm("v_cvt_pk_bf16_f32 %0, %1, %2" : "=v"(plo) : "v"(p0), "v"(p1));
        asm("v_cvt_pk_bf16_f32 %0, %1, %2" : "=v"(phi) : "v"(p2), "v"(p3));
        const uint2v pk2 = {plo, phi};
        Pf[mi][ni] = __builtin_bit_cast(short4v, pk2);
      }

    // O^T += V^T * P^T  (V A-frags from swizzled LDS tile: 2 bases + imms)
    const u16* VsA = &Vd[jt & 1][b0];
    const u16* VsB = &Vd[jt & 1][b1];
    __builtin_amdgcn_s_setprio(1);
#pragma unroll
    for (int np = 0; np < 2; ++np)
#pragma unroll
      for (int ni2 = 0; ni2 < 4; ++ni2) {
        const short8 vv =
            *(const short8*)((np ? VsB : VsA) + ni2 * 1024);
        const short4v va = {vv[0], vv[1], vv[2], vv[3]};    // keys ni=2np
        const short4v vb2 = {vv[4], vv[5], vv[6], vv[7]};   // keys ni=2np+1
        O[0][ni2] = mfma16(va, Pf[0][2 * np], O[0][ni2]);
        O[0][ni2] = mfma16(vb2, Pf[0][2 * np + 1], O[0][ni2]);
        O[1][ni2] = mfma16(va, Pf[1][2 * np], O[1][ni2]);
        O[1][ni2] = mfma16(vb2, Pf[1][2 * np + 1], O[1][ni2]);
      }
    __builtin_amdgcn_s_setprio(0);
  }

  // epilogue: reduce l over quads, scale, packed 8B stores
#pragma unroll
  for (int mi = 0; mi < 2; ++mi) {
    float s = l_[mi];
    s += __shfl_xor(s, 16, 64);
    s += __shfl_xor(s, 32, 64);
    const float rl = __builtin_amdgcn_rcpf(s);
#pragma unroll
    for (int ni2 = 0; ni2 < 4; ++ni2) {
      short4v o;
#pragma unroll
      for (int e = 0; e < 4; ++e) o[e] = (short)f2bf(O[mi][ni2][e] * rl);
      *(short4v*)(Ob + (size_t)(b * Sn + qb64 + w * 32 + mi * 16 + r) * Dn +
                  h * 64 + ni2 * 16 + q * 4) = o;
    }
  }
}

// ---------------------------------------------------------------------------
extern "C" void kernel_launch(void* const* d_in, const int* in_sizes, int n_in,
                              void* d_out, int out_size, void* d_ws, size_t ws_size,
                              hipStream_t stream) {
  const float* x  = (const float*)d_in[0];
  const float* wq = (const float*)d_in[1];
  const float* wk = (const float*)d_in[2];
  const float* wv = (const float*)d_in[3];
  const float* wo = (const float*)d_in[4];
  float* out = (float*)d_out;

  u16* xb  = (u16*)d_ws;            // 8M u16
  u16* wqb = xb + 8388608;
  u16* wkb = wqb + 1048576;
  u16* wvb = wkb + 1048576;
  u16* wob = wvb + 1048576;
  u16* qb  = wob + 1048576;         // 8M each
  u16* kb  = qb + 8388608;
  u16* vt2 = kb + 8388608;          // V^T tiles, pre-swizzled
  u16* aob = vt2 + 8388608;

  cast_all<<<12288, 256, 0, stream>>>(
      (const float4*)x, (const float4*)wq, (const float4*)wk,
      (const float4*)wv, (const float4*)wo, (ushort4*)xb, (ushort4*)wqb,
      (ushort4*)wkb, (ushort4*)wvb, (ushort4*)wob);

  gemm_qkv<<<dim3(64, 8, 3), 256, 0, stream>>>(xb, wqb, wkb, wvb, qb, kb, vt2);

  attn_v9<<<2048, 128, 0, stream>>>(qb, kb, vt2, aob);

  gemm_out<<<dim3(64, 8), 256, 0, stream>>>(aob, wob, out);
}

// Round 6
// 220.363 us; speedup vs baseline: 1.2284x; 1.0928x over previous
//
#include <hip/hip_runtime.h>
#include <math.h>

typedef unsigned short u16;
typedef __attribute__((ext_vector_type(8))) short short8;   // 8 bf16 = 4 VGPRs
typedef __attribute__((ext_vector_type(4))) short short4v;  // 4 bf16 = 2 VGPRs
typedef __attribute__((ext_vector_type(4))) float f32x4;    // MFMA C/D frag
typedef __attribute__((ext_vector_type(2))) unsigned int uint2v;
typedef __attribute__((ext_vector_type(4))) unsigned int uint4v;

constexpr int Bn = 4, Sn = 2048, Dn = 1024, Hn = 16;
constexpr float SCL = 0.125f * 1.44269504f;  // 1/sqrt(64) * log2(e), folded into Wq

__device__ __forceinline__ u16 f2bf(float f) {  // RNE float->bf16
  unsigned u = __float_as_uint(f);
  u += 0x7fffu + ((u >> 16) & 1u);
  return (u16)(u >> 16);
}

__device__ __forceinline__ f32x4 mfma32(short8 a, short8 b, f32x4 c) {
  return __builtin_amdgcn_mfma_f32_16x16x32_bf16(a, b, c, 0, 0, 0);
}

__device__ __forceinline__ void gl_lds16(const u16* g, u16* l) {
  __builtin_amdgcn_global_load_lds(
      (const __attribute__((address_space(1))) unsigned int*)g,
      (__attribute__((address_space(3))) unsigned int*)l, 16, 0, 0);
}

// ---------------------------------------------------------------------------
// One launch for all f32->bf16 casts. Blocks 0..8191: x. Then 1024 each for
// wq (pre-scaled by SCL), wk, wv, wo.
// ---------------------------------------------------------------------------
__global__ __launch_bounds__(256) void cast_all(
    const float4* __restrict__ x, const float4* __restrict__ wq,
    const float4* __restrict__ wk, const float4* __restrict__ wv,
    const float4* __restrict__ wo, ushort4* __restrict__ xb,
    ushort4* __restrict__ wqb, ushort4* __restrict__ wkb,
    ushort4* __restrict__ wvb, ushort4* __restrict__ wob) {
  const int blk = blockIdx.x;
  const float4* in;
  ushort4* out;
  int base;
  float s = 1.0f;
  if (blk < 8192) {
    in = x; out = xb; base = blk;
  } else if (blk < 9216) {
    in = wq; out = wqb; base = blk - 8192; s = SCL;
  } else if (blk < 10240) {
    in = wk; out = wkb; base = blk - 9216;
  } else if (blk < 11264) {
    in = wv; out = wvb; base = blk - 10240;
  } else {
    in = wo; out = wob; base = blk - 11264;
  }
  const int i = base * 256 + threadIdx.x;
  const float4 f = in[i];
  ushort4 o;
  o.x = f2bf(f.x * s); o.y = f2bf(f.y * s);
  o.z = f2bf(f.z * s); o.w = f2bf(f.w * s);
  out[i] = o;
}

// ---------------------------------------------------------------------------
// C[m,n] = sum_k A[m,k]*W[n,k], bf16 in. 128x128 tile, BK=64, 4 waves.
// m97 two-barrier structure; LDS declared once at kernel scope (shared by
// both gemm_body instantiations in gemm_qkv). Swizzle cl^(row&7).
// MODE 0: bf16 natural; MODE 1: f32 natural; MODE 2: bf16 into vt2 = V^T
// tiles [hd][key] (64x64 per (b,h,jt)), 16B chunks XOR-swizzled by hd
// (matches attn's identity-copy LDS staging + swizzled reads).
// ---------------------------------------------------------------------------
template <int MODE>
__device__ __forceinline__ void gemm_body(const u16* __restrict__ A,
                                          const u16* __restrict__ W,
                                          u16* __restrict__ Cb,
                                          float* __restrict__ Cf,
                                          int bx, int by,
                                          u16* __restrict__ Asm,
                                          u16* __restrict__ Wsm) {
  const int t = threadIdx.x;
  const int w = t >> 6, l = t & 63;
  const int wy = w >> 1, wx = w & 1;
  const int q = l >> 4, r = l & 15;
  const int m0 = bx * 128, n0 = by * 128;

  f32x4 acc[4][4] = {};

  for (int k0 = 0; k0 < 1024; k0 += 64) {
    __syncthreads();
#pragma unroll
    for (int i = 0; i < 4; ++i) {
      const int c = t + i * 256;            // 16B chunk id, 0..1023
      const int row = c >> 3, cl = c & 7;   // 8 chunks per 128B row
      const int cg = cl ^ (row & 7);        // pre-swizzled global source
      gl_lds16(A + (size_t)(m0 + row) * 1024 + k0 + cg * 8, &Asm[c * 8]);
      gl_lds16(W + (size_t)(n0 + row) * 1024 + k0 + cg * 8, &Wsm[c * 8]);
    }
    __syncthreads();
#pragma unroll
    for (int kf = 0; kf < 2; ++kf) {
      short8 af[4], bf[4];
#pragma unroll
      for (int mi = 0; mi < 4; ++mi) {
        const int rowA = wy * 64 + mi * 16 + r;
        af[mi] = *(const short8*)&Asm[rowA * 64 + ((kf * 4 + q) ^ (rowA & 7)) * 8];
        const int rowB = wx * 64 + mi * 16 + r;
        bf[mi] = *(const short8*)&Wsm[rowB * 64 + ((kf * 4 + q) ^ (rowB & 7)) * 8];
      }
#pragma unroll
      for (int mi = 0; mi < 4; ++mi)
#pragma unroll
        for (int ni = 0; ni < 4; ++ni)
          acc[mi][ni] = mfma32(af[mi], bf[ni], acc[mi][ni]);
    }
  }

  if (MODE == 2) {
    // acc[mi][ni][e]: token = m0+wy*64+mi*16+q*4+e, feat = n0+wx*64+ni*16+r.
    // -> vt2 tile (b, h, jt): V^T[hd=ni*16+r][key=mi*16+q*4+e], stored as
    // 16B chunks c2 = q + 4*(mi>>1) at slot c2^(hd&7), half (mi&1).
    const int bq = m0 >> 11;
    const int jt = ((m0 & 2047) >> 6) + wy;
    const int hh = (n0 >> 6) + wx;
    u16* vt_t = Cb + ((size_t)((bq * 16 + hh) * 32) + jt) * 4096;
#pragma unroll
    for (int mi = 0; mi < 4; ++mi)
#pragma unroll
      for (int ni = 0; ni < 4; ++ni) {
        short4v pk;
#pragma unroll
        for (int e = 0; e < 4; ++e) pk[e] = (short)f2bf(acc[mi][ni][e]);
        const int hd = ni * 16 + r;
        const int c2 = q + 4 * (mi >> 1);
        *(short4v*)&vt_t[hd * 64 + ((c2 ^ (r & 7)) * 8) + (mi & 1) * 4] = pk;
      }
    return;
  }

#pragma unroll
  for (int mi = 0; mi < 4; ++mi) {
    const int row = m0 + wy * 64 + mi * 16 + q * 4;
#pragma unroll
    for (int ni = 0; ni < 4; ++ni) {
      const int col = n0 + wx * 64 + ni * 16 + r;
#pragma unroll
      for (int e = 0; e < 4; ++e) {
        if (MODE == 1)
          Cf[(size_t)(row + e) * 1024 + col] = acc[mi][ni][e];
        else
          Cb[(size_t)(row + e) * 1024 + col] = f2bf(acc[mi][ni][e]);
      }
    }
  }
}

__global__ __launch_bounds__(256) void gemm_qkv(const u16* __restrict__ A,
                                                const u16* __restrict__ Wq,
                                                const u16* __restrict__ Wk,
                                                const u16* __restrict__ Wv,
                                                u16* __restrict__ Cq,
                                                u16* __restrict__ Ck,
                                                u16* __restrict__ Vt) {
  __shared__ u16 Asm[128 * 64];
  __shared__ u16 Wsm[128 * 64];
  const int z = blockIdx.z;
  if (z == 2)
    gemm_body<2>(A, Wv, Vt, nullptr, blockIdx.x, blockIdx.y, Asm, Wsm);
  else
    gemm_body<0>(A, z ? Wk : Wq, z ? Ck : Cq, nullptr, blockIdx.x, blockIdx.y,
                 Asm, Wsm);
}

__global__ __launch_bounds__(256) void gemm_out(const u16* __restrict__ A,
                                                const u16* __restrict__ W,
                                                float* __restrict__ C) {
  __shared__ u16 Asm[128 * 64];
  __shared__ u16 Wsm[128 * 64];
  gemm_body<1>(A, W, nullptr, C, blockIdx.x, blockIdx.y, Asm, Wsm);
}

// ---------------------------------------------------------------------------
// Flash attention v10 = v9 (LPT grid) + two changes:
//
// (1) LDS 32->24 KB: V is SINGLE-buffered. V(jt) isn't consumed until after
//     QK+exp (~500 cy), so stage it at iter start (right after the barrier
//     that retired V(jt-1)'s reads) and wait for it with a COUNTED
//     s_waitcnt vmcnt(4) + raw s_barrier just before PV (T4: the 4 K(jt+1)
//     prefetch loads, issued after V's 4, stay in flight across this
//     barrier -- never drained mid-iter; they retire at the NEXT iter-start
//     __syncthreads). 24 KB/block -> 6 blocks/CU (was 4-5): +50% resident
//     waves on a latency-bound kernel (v9: MFMA 30/VALU 39/occ 17.6 -- no
//     pipe saturated).
// (2) PV uses mfma32 (16x16x32) instead of 32x mfma16: vv[np][ni2]'s 8
//     values per lane are keys {32np+q*4+0..3, 32np+16+q*4+0..3} -- a
//     per-quad permutation of the A-frag k-order; the matching B-frag is
//     concat(Pf[mi][2np], Pf[mi][2np+1]) which falls directly out of the
//     cvt_pk words. k is a contraction dim, so any bijection shared by A
//     and B is exact. Halves PV issue count (32 -> 16 per wave-iter).
//
// Retained: LPT dispatch (heavy st first), XCD pinning, K double-buffer w/
// full-iter prefetch span, register softmax via S^T trick, scale pre-folded
// into Wq, setprio on MFMA clusters.
// ---------------------------------------------------------------------------
__global__ __launch_bounds__(128) void attn_v10(const u16* __restrict__ Qb,
                                                const u16* __restrict__ Kb,
                                                const u16* __restrict__ Vt,
                                                u16* __restrict__ Ob) {
  const int i = blockIdx.x;                      // 0..2047
  const int st = 31 - (i >> 6);                  // heavy q-tiles first (LPT)
  const int grp = (i & 7) + 8 * ((i >> 3) & 7);  // (b,h) group, XCD-pinned
  const int b = grp >> 4, h = grp & 15;
  const int t = threadIdx.x;
  const int w = t >> 6, l = t & 63;
  const int q = l >> 4, r = l & 15;

  __shared__ u16 Kd[2][4096];   // K double buffer (16 KB)
  __shared__ u16 Vd[4096];      // V single buffer (8 KB)

  const size_t kgbase = (size_t)(b * Sn) * Dn + h * 64;
  const size_t vgbase = (size_t)((b * Hn + h) * 32) * 4096;

  // Per-thread global staging pointers.
  const u16* kg[4];
  const u16* vg[4];
#pragma unroll
  for (int ii = 0; ii < 4; ++ii) {
    const int c = t + ii * 128, row = c >> 3, cl = c & 7;
    kg[ii] = Kb + kgbase + (size_t)row * Dn + (cl ^ (row & 7)) * 8;
    vg[ii] = Vt + vgbase + c * 8;
  }
  // Hoisted LDS read bases (elements). K kf=0/1 and V np=0/1 use the same
  // swizzle: base = r*64 + ((kf*4+q)^(r&7))*8.
  const int rx = r & 7;
  const int b0 = r * 64 + ((q ^ rx) * 8);
  const int b1 = r * 64 + (((4 + q) ^ rx) * 8);

  const int qb64 = st * 64;

  // Q B-frags (n = qrow = lane&15, k = hd = quad*8+j); Q pre-scaled by SCL
  short8 Qf[2][2];
#pragma unroll
  for (int mi = 0; mi < 2; ++mi)
#pragma unroll
    for (int kf = 0; kf < 2; ++kf)
      Qf[mi][kf] = *(const short8*)(Qb +
          (size_t)(b * Sn + qb64 + w * 32 + mi * 16 + r) * Dn + h * 64 +
          kf * 32 + q * 8);

  f32x4 O[2][4] = {};
  float l_[2] = {0.f, 0.f};

  // prologue: stage K(0) -> Kd[0] (V(0) is staged inside iter 0)
#pragma unroll
  for (int ii = 0; ii < 4; ++ii)
    gl_lds16(kg[ii], &Kd[0][(t + ii * 128) * 8]);

  // Running prefetch pointers: K from tile 1, V from tile 0.
  const u16* kgt[4];
  const u16* vgt[4];
#pragma unroll
  for (int ii = 0; ii < 4; ++ii) {
    kgt[ii] = kg[ii] + 64 * Dn;
    vgt[ii] = vg[ii];
  }

  for (int jt = 0; jt <= st; ++jt) {
    __syncthreads();  // vmcnt(0)+barrier: K(jt) staged; V(jt-1) reads done

    // issue V(jt) -> Vd (4 loads, FIRST: vmcnt(4) below waits exactly these)
#pragma unroll
    for (int ii = 0; ii < 4; ++ii) {
      gl_lds16(vgt[ii], &Vd[(t + ii * 128) * 8]);
      vgt[ii] += 4096;
    }
    // issue K(jt+1) -> other K buffer (4 loads; span the whole iteration)
    if (jt < st) {
      u16* kl = &Kd[(jt + 1) & 1][0];
#pragma unroll
      for (int ii = 0; ii < 4; ++ii) {
        gl_lds16(kgt[ii], kl + (t + ii * 128) * 8);
        kgt[ii] += 64 * Dn;
      }
    }

    const u16* KtA = &Kd[jt & 1][b0];
    const u16* KtB = &Kd[jt & 1][b1];

    // K A-frags (m = key = lane&15, k = hd): 2 bases + imm offsets
    short8 Kf[4][2];
#pragma unroll
    for (int ni = 0; ni < 4; ++ni) {
      Kf[ni][0] = *(const short8*)(KtA + ni * 1024);
      Kf[ni][1] = *(const short8*)(KtB + ni * 1024);
    }

    // S^T[key][qrow]: A=K, B=Q (already includes softmax scale via Wq)
    f32x4 S[2][4] = {};
    __builtin_amdgcn_s_setprio(1);
#pragma unroll
    for (int ni = 0; ni < 4; ++ni)
#pragma unroll
      for (int kf = 0; kf < 2; ++kf) {
        S[0][ni] = mfma32(Kf[ni][kf], Qf[0][kf], S[0][ni]);
        S[1][ni] = mfma32(Kf[ni][kf], Qf[1][kf], S[1][ni]);
      }
    __builtin_amdgcn_s_setprio(0);

    // causal mask on diagonal tile (local: key = ni*16+q*4+e, row = w*32+mi*16+r)
    if (jt == st) {
#pragma unroll
      for (int mi = 0; mi < 2; ++mi) {
        const int qrow = w * 32 + mi * 16 + r;
#pragma unroll
        for (int ni = 0; ni < 4; ++ni) {
          const int key = ni * 16 + q * 4;
#pragma unroll
          for (int e = 0; e < 4; ++e)
            if (key + e > qrow) S[mi][ni][e] = -3.0e38f;
        }
      }
    }

    // exp2 (scale pre-folded) -> P8[mi][np] = full K=32 B-frag for PV:
    // words {cvtpk(ni=2np), cvtpk(ni=2np+1)} = keys {32np+q*4+0..3,
    // 32np+16+q*4+0..3} -- matches vv's A-frag key order per quad.
    short8 P8[2][2];
#pragma unroll
    for (int mi = 0; mi < 2; ++mi)
#pragma unroll
      for (int np = 0; np < 2; ++np) {
        unsigned pw[4];
#pragma unroll
        for (int half = 0; half < 2; ++half) {
          const int ni = 2 * np + half;
          const float p0 = __builtin_amdgcn_exp2f(S[mi][ni][0]);
          const float p1 = __builtin_amdgcn_exp2f(S[mi][ni][1]);
          const float p2 = __builtin_amdgcn_exp2f(S[mi][ni][2]);
          const float p3 = __builtin_amdgcn_exp2f(S[mi][ni][3]);
          l_[mi] += (p0 + p1) + (p2 + p3);
          unsigned plo, phi;
          asm("v_cvt_pk_bf16_f32 %0, %1, %2" : "=v"(plo) : "v"(p0), "v"(p1));
          asm("v_cvt_pk_bf16_f32 %0, %1, %2" : "=v"(phi) : "v"(p2), "v"(p3));
          pw[half * 2] = plo;
          pw[half * 2 + 1] = phi;
        }
        const uint4v pk4 = {pw[0], pw[1], pw[2], pw[3]};
        P8[mi][np] = __builtin_bit_cast(short8, pk4);
      }

    // wait for V(jt) in LDS: counted vmcnt keeps K(jt+1) in flight.
    if (jt < st)
      asm volatile("s_waitcnt vmcnt(4)" ::: "memory");
    else
      asm volatile("s_waitcnt vmcnt(0)" ::: "memory");
    __builtin_amdgcn_s_barrier();
    __builtin_amdgcn_sched_barrier(0);

    // O^T += V^T * P^T via mfma32: A = vv (V^T, 8 keys/lane), B = P8.
    __builtin_amdgcn_s_setprio(1);
#pragma unroll
    for (int np = 0; np < 2; ++np) {
      const int vb = np ? b1 : b0;
#pragma unroll
      for (int ni2 = 0; ni2 < 4; ++ni2) {
        const short8 vvx = *(const short8*)(&Vd[vb + ni2 * 1024]);
        O[0][ni2] = mfma32(vvx, P8[0][np], O[0][ni2]);
        O[1][ni2] = mfma32(vvx, P8[1][np], O[1][ni2]);
      }
    }
    __builtin_amdgcn_s_setprio(0);
  }

  // epilogue: reduce l over quads, scale, packed 8B stores
#pragma unroll
  for (int mi = 0; mi < 2; ++mi) {
    float s = l_[mi];
    s += __shfl_xor(s, 16, 64);
    s += __shfl_xor(s, 32, 64);
    const float rl = __builtin_amdgcn_rcpf(s);
#pragma unroll
    for (int ni2 = 0; ni2 < 4; ++ni2) {
      short4v o;
#pragma unroll
      for (int e = 0; e < 4; ++e) o[e] = (short)f2bf(O[mi][ni2][e] * rl);
      *(short4v*)(Ob + (size_t)(b * Sn + qb64 + w * 32 + mi * 16 + r) * Dn +
                  h * 64 + ni2 * 16 + q * 4) = o;
    }
  }
}

// ---------------------------------------------------------------------------
extern "C" void kernel_launch(void* const* d_in, const int* in_sizes, int n_in,
                              void* d_out, int out_size, void* d_ws, size_t ws_size,
                              hipStream_t stream) {
  const float* x  = (const float*)d_in[0];
  const float* wq = (const float*)d_in[1];
  const float* wk = (const float*)d_in[2];
  const float* wv = (const float*)d_in[3];
  const float* wo = (const float*)d_in[4];
  float* out = (float*)d_out;

  u16* xb  = (u16*)d_ws;            // 8M u16
  u16* wqb = xb + 8388608;
  u16* wkb = wqb + 1048576;
  u16* wvb = wkb + 1048576;
  u16* wob = wvb + 1048576;
  u16* qb  = wob + 1048576;         // 8M each
  u16* kb  = qb + 8388608;
  u16* vt2 = kb + 8388608;          // V^T tiles, pre-swizzled
  u16* aob = vt2 + 8388608;

  cast_all<<<12288, 256, 0, stream>>>(
      (const float4*)x, (const float4*)wq, (const float4*)wk,
      (const float4*)wv, (const float4*)wo, (ushort4*)xb, (ushort4*)wqb,
      (ushort4*)wkb, (ushort4*)wvb, (ushort4*)wob);

  gemm_qkv<<<dim3(64, 8, 3), 256, 0, stream>>>(xb, wqb, wkb, wvb, qb, kb, vt2);

  attn_v10<<<2048, 128, 0, stream>>>(qb, kb, vt2, aob);

  gemm_out<<<dim3(64, 8), 256, 0, stream>>>(aob, wob, out);
}